// Round 18
// baseline (109.513 us; speedup 1.0000x reference)
//
#include <hip/hip_runtime.h>
#include <math.h>

#define Lc 13
#define Hc 1024
#define Bc 32
#define Sc 2048
#define BSc (Bc*Sc)
#define CHUNK 128
#define NCHUNK 16
#define NBLK (Bc*NCHUNK)   // 512 chunk blocks

#define INV_LN2 1.44269504088896340736f
#define LN2f    0.69314718055994530942f

#if __has_builtin(__builtin_amdgcn_exp2f)
#define EXP2F(x) __builtin_amdgcn_exp2f(x)
#else
#define EXP2F(x) exp2f(x)
#endif
#if __has_builtin(__builtin_amdgcn_logf)
#define LOG2F(x) __builtin_amdgcn_logf(x)
#else
#define LOG2F(x) log2f(x)
#endif

typedef __attribute__((ext_vector_type(8))) short short8v;   // 8 bf16 = 4 VGPR
typedef __attribute__((ext_vector_type(4))) float f32x4v;    // MFMA acc

union FragU { unsigned u[4]; short8v v; };

// RNE-round pair (x0,x1) to bf16: hi word-pair, plus lo = RNE(x - hi) pair.
__device__ __forceinline__ void packpair(float x0, float x1,
                                         unsigned& hi, unsigned& lo) {
  unsigned u0 = __float_as_uint(x0), u1 = __float_as_uint(x1);
  unsigned r0 = (u0 + 0x7FFFu + ((u0 >> 16) & 1u)) >> 16;
  unsigned r1 = (u1 + 0x7FFFu + ((u1 >> 16) & 1u)) >> 16;
  hi = r0 | (r1 << 16);
  float l0 = x0 - __uint_as_float(r0 << 16);
  float l1 = x1 - __uint_as_float(r1 << 16);
  unsigned v0 = __float_as_uint(l0), v1 = __float_as_uint(l1);
  unsigned s0 = (v0 + 0x7FFFu + ((v0 >> 16) & 1u)) >> 16;
  unsigned s1 = (v1 + 0x7FFFu + ((v1 >> 16) & 1u)) >> 16;
  lo = s0 | (s1 << 16);
}

// ---------------------------------------------------------------------------
// Kernel A: logits = hs @ W^T + b via MFMA 16x16x32 bf16.
// Every VALU-loop variant plateaued at ~85us (2x the 43us HBM floor) -- the
// invariant was the FMA dot itself (~2500 VALU/wave/8rows). MFMA removes it:
// wave = 16 rows, 32 K-chunks, acc = mfma(Ahi,W,acc); acc = mfma(Alo,W,acc)
// (split-bf16 A: error ~ W-bf16 alone, which measured absmax 0.0156, passes).
// Layouts (ISA/guide): A row=lane&15, k=(lane>>4)*8+j; B col=lane&15, same k;
// C/D col=lane&15, row=(lane>>4)*4+reg [HW-verified m89/m91]. W fragment
// table precomputed in LDS (32KB, one ds_read_b128/chunk, conflict-free).
// Depth-1 ping-pong A prefetch (static slots). (512,2): proven spill-free.
// Per-SIMD cost: pack ~10us, LDS ~3us, MFMA ~2us << HBM 43us -> mem-bound.
// ---------------------------------------------------------------------------
__global__ __launch_bounds__(512, 2)
void k_logits(const float* __restrict__ A, const float* __restrict__ W,
              const float* __restrict__ bias, float* __restrict__ out) {
  __shared__ unsigned Wl[32 * 64 * 4];   // [chunk][lane][reg] : 32 KB
  const int tid = threadIdx.x;
  const int ln  = tid & 63;
  const int wv  = tid >> 6;              // 0..7
  const int n16 = ln & 15;               // A-row / B-col / D-col lane role
  const int kg  = ln >> 4;               // k-group 0..3
  const size_t rowBase = ((size_t)blockIdx.x * 8 + wv) * 16;

  const float* Ar = A + (rowBase + n16) * (size_t)Hc + (kg << 3);

  // prefetch chunk 0 (8 floats/lane) before W staging
  float4 a0 = *(const float4*)(Ar);
  float4 a1 = *(const float4*)(Ar + 4);
  __builtin_amdgcn_sched_barrier(0);

  // stage W fragment table: idx -> chunk c, lane l, reg p.
  // lane l supplies col=l&15, k = c*32 + (l>>4)*8 + p*2 (+1 in hi half).
#pragma unroll
  for (int i = 0; i < 16; ++i) {
    int idx = tid + i * 512;
    int c = idx >> 8, l = (idx >> 2) & 63, p = idx & 3;
    int wcol = l & 15;
    int kb = c * 32 + ((l >> 4) << 3) + p * 2;
    unsigned v = 0u;
    if (wcol < Lc) {
      float w0 = W[wcol * Hc + kb], w1 = W[wcol * Hc + kb + 1];
      unsigned q0 = __float_as_uint(w0), q1 = __float_as_uint(w1);
      unsigned r0 = (q0 + 0x7FFFu + ((q0 >> 16) & 1u)) >> 16;
      unsigned r1 = (q1 + 0x7FFFu + ((q1 >> 16) & 1u)) >> 16;
      v = r0 | (r1 << 16);
    }
    Wl[idx] = v;
  }
  __syncthreads();

  f32x4v acc = {0.f, 0.f, 0.f, 0.f};
  float4 b0, b1;   // ping-pong slot

#pragma unroll
  for (int c = 0; c < 32; ++c) {
    float4 x0, x1;
    if (c & 1) { x0 = b0; x1 = b1; } else { x0 = a0; x1 = a1; }
    if (c + 1 < 32) {   // issue next chunk's loads before packing/mfma
      const float* np = Ar + (c + 1) * 32;
      if (c & 1) { a0 = *(const float4*)np; a1 = *(const float4*)(np + 4); }
      else       { b0 = *(const float4*)np; b1 = *(const float4*)(np + 4); }
    }
    FragU fh, fl;
    packpair(x0.x, x0.y, fh.u[0], fl.u[0]);
    packpair(x0.z, x0.w, fh.u[1], fl.u[1]);
    packpair(x1.x, x1.y, fh.u[2], fl.u[2]);
    packpair(x1.z, x1.w, fh.u[3], fl.u[3]);
    FragU fw;
    {
      uint4 wq = *(const uint4*)&Wl[(c * 64 + ln) * 4];   // ds_read_b128
      fw.u[0] = wq.x; fw.u[1] = wq.y; fw.u[2] = wq.z; fw.u[3] = wq.w;
    }
    acc = __builtin_amdgcn_mfma_f32_16x16x32_bf16(fh.v, fw.v, acc, 0, 0, 0);
    acc = __builtin_amdgcn_mfma_f32_16x16x32_bf16(fl.v, fw.v, acc, 0, 0, 0);
  }

  // D: col = ln&15 (= n16), row = kg*4 + reg  [HW-verified layout]
  if (n16 < Lc) {
    float bl = bias[n16];
    out[(rowBase + kg * 4 + 0) * Lc + n16] = acc[0] + bl;
    out[(rowBase + kg * 4 + 1) * Lc + n16] = acc[1] + bl;
    out[(rowBase + kg * 4 + 2) * Lc + n16] = acc[2] + bl;
    out[(rowBase + kg * 4 + 3) * Lc + n16] = acc[3] + bl;
  }
}

// ---------------------------------------------------------------------------
// Kernel B: per (batch, chunk) 13x13 transfer matrix, LINEAR domain
// (13 shfl + 13 fma + 1 exp2 per step; exponent-extract renorm every 8).
// Wave 0 also computes the chunk's numerator partial. Block 0 zeroes out0.
// ---------------------------------------------------------------------------
__global__ void k_chunks(const float* __restrict__ logits, const int* __restrict__ mask,
                         const int* __restrict__ labels, const float* __restrict__ T,
                         float* __restrict__ Mout, float* __restrict__ numpart,
                         float* __restrict__ cntpart, float* __restrict__ out0) {
  const int bp = blockIdx.x;
  const int b  = bp >> 4;       // NCHUNK == 16
  const int p  = bp & 15;
  const int tid = threadIdx.x;
  if (bp == 0 && tid == 0) out0[0] = 0.f;   // zero loss accumulator for k_final
  const int g = tid >> 4;
  const int k = tid & 15;
  const int kk = (k < 13) ? k : 0;
  const int gg = (g < 13) ? g : 0;
  const bool active = (g < 13) && (k < 13);
  const size_t lbase = (size_t)b * Sc;
  const int t0 = 1 + p * CHUNK;
  const int t1 = min(t0 + CHUNK, Sc);

  float U[13];   // column kk of exp(T)
#pragma unroll
  for (int j = 0; j < 13; ++j) U[j] = EXP2F(T[j * 13 + kk] * INV_LN2);

  float e0 = logits[(lbase + t0) * Lc + kk] * INV_LN2;
  int   m0 = mask[lbase + t0];
  float P = m0 ? EXP2F(T[gg * 13 + kk] * INV_LN2 + e0) : ((g == k) ? 1.f : 0.f);
  float off = 0.f;

  for (int t = t0 + 1; t < t1; ++t) {
    float e2 = logits[(lbase + t) * Lc + kk] * INV_LN2;
    int   mk = mask[lbase + t];
    float pj[13];
#pragma unroll
    for (int j = 0; j < 13; ++j) pj[j] = __shfl(P, j, 16);
    float s0 = pj[0] * U[0];  s0 = fmaf(pj[4],  U[4],  s0);
    s0 = fmaf(pj[8],  U[8],  s0);  s0 = fmaf(pj[12], U[12], s0);
    float s1 = pj[1] * U[1];  s1 = fmaf(pj[5],  U[5],  s1);  s1 = fmaf(pj[9],  U[9],  s1);
    float s2 = pj[2] * U[2];  s2 = fmaf(pj[6],  U[6],  s2);  s2 = fmaf(pj[10], U[10], s2);
    float s3 = pj[3] * U[3];  s3 = fmaf(pj[7],  U[7],  s3);  s3 = fmaf(pj[11], U[11], s3);
    float s = (s0 + s1) + (s2 + s3);
    float Pn = EXP2F(e2) * s;
    P = mk ? Pn : P;
    if (((t - t0) & 7) == 0) {   // renorm: keep row max in [1,2)
      float mx = P;
#pragma unroll
      for (int o = 1; o < 16; o <<= 1) mx = fmaxf(mx, __shfl_xor(mx, o, 16));
      unsigned eb = (__float_as_uint(mx) >> 23) & 255u;
      float scale = __uint_as_float((254u - eb) << 23);   // 2^(127-eb)
      P *= scale;
      off += (float)((int)eb - 127);
    }
  }
  if (active) Mout[(size_t)bp * 169 + g * 13 + k] = (P > 0.f) ? (LOG2F(P) + off) : -1e30f;

  // ---- numerator partial for this chunk's tokens [t0, t1) ----
  if (tid < 64) {
    float np = 0.f; int cnt = 0;
    for (int t = t0 + tid; t < t1; t += 64) {
      int mk = mask[lbase + t];
      if (mk) {
        int tg = labels[lbase + t];
        int pg = labels[lbase + t - 1];
        np += T[pg * 13 + tg] + logits[(lbase + t) * Lc + tg];
        cnt += 1;
      }
    }
#pragma unroll
    for (int o = 1; o < 64; o <<= 1) {
      np  += __shfl_xor(np, o, 64);
      cnt += __shfl_xor(cnt, o, 64);
    }
    if (tid == 0) { numpart[bp] = np; cntpart[bp] = (float)cnt; }
  }
}

// ---------------------------------------------------------------------------
// Kernel C: per batch: combine 16 chunk matrices (log2 domain) -> denominator;
// assemble numerator from partials; atomicAdd loss.
// ---------------------------------------------------------------------------
__global__ void k_final(const float* __restrict__ logits, const int* __restrict__ mask,
                        const int* __restrict__ labels, const float* __restrict__ startT,
                        const float* __restrict__ endT, const float* __restrict__ Mws,
                        const float* __restrict__ numpart, const float* __restrict__ cntpart,
                        float* __restrict__ out0) {
  const int b = blockIdx.x;
  const int lane = threadIdx.x;
  const int kk = (lane < 13) ? lane : 0;
  const size_t lbase = (size_t)b * Sc;

  // ---- denominator (log2 domain) ----
  float v = (startT[kk] + logits[lbase * Lc + kk]) * INV_LN2;
  for (int p = 0; p < NCHUNK; ++p) {
    const float* Mp = Mws + (size_t)(b * NCHUNK + p) * 169;
    float a[13];
#pragma unroll
    for (int j = 0; j < 13; ++j) a[j] = __shfl(v, j, 64) + Mp[j * 13 + kk];
    float mx = a[0];
#pragma unroll
    for (int j = 1; j < 13; ++j) mx = fmaxf(mx, a[j]);
    float s = 0.f;
#pragma unroll
    for (int j = 0; j < 13; ++j) s += EXP2F(a[j] - mx);
    v = mx + LOG2F(s);
  }
  float x = (lane < 13) ? (v + endT[kk] * INV_LN2) : -1e30f;
  float mx = x;
#pragma unroll
  for (int off = 1; off < 16; off <<= 1) mx = fmaxf(mx, __shfl_xor(mx, off, 16));
  float sx = EXP2F(x - mx);
#pragma unroll
  for (int off = 1; off < 16; off <<= 1) sx += __shfl_xor(sx, off, 16);
  float den = (mx + LOG2F(sx)) * LN2f;   // valid on lanes 0..15

  // ---- numerator from chunk partials (lanes 0..15) ----
  float np = 0.f, cs = 0.f;
  if (lane < NCHUNK) { np = numpart[b * NCHUNK + lane]; cs = cntpart[b * NCHUNK + lane]; }
#pragma unroll
  for (int o = 1; o < 16; o <<= 1) {
    np += __shfl_xor(np, o, 16);
    cs += __shfl_xor(cs, o, 16);
  }
  if (lane == 0) {
    int lab0 = labels[lbase];
    int seqlen = mask[lbase] + (int)(cs + 0.5f);
    int lastTag = labels[lbase + seqlen - 1];
    float num = startT[lab0] + logits[lbase * Lc + lab0] + np + endT[lastTag];
    float llh = num - den;
    atomicAdd(out0, -llh * (1.0f / Bc));
  }
}

extern "C" void kernel_launch(void* const* d_in, const int* in_sizes, int n_in,
                              void* d_out, int out_size, void* d_ws, size_t ws_size,
                              hipStream_t stream) {
  const float* hs     = (const float*)d_in[0];
  const int*   amask  = (const int*)d_in[1];
  const int*   labels = (const int*)d_in[2];
  const float* W      = (const float*)d_in[3];
  const float* bias   = (const float*)d_in[4];
  const float* startT = (const float*)d_in[5];
  const float* endT   = (const float*)d_in[6];
  const float* T      = (const float*)d_in[7];

  float* out    = (float*)d_out;
  float* logits = out + 1;            // output 1 follows the scalar loss
  float* Mws    = (float*)d_ws;       // 512*169 floats = 346 KB
  float* numpart = Mws + (size_t)NBLK * 169;
  float* cntpart = numpart + NBLK;    // total ~350 KB of ws

  k_logits<<<BSc / 128, 512, 0, stream>>>(hs, W, bias, logits);
  k_chunks<<<NBLK, 256, 0, stream>>>(logits, amask, labels, T, Mws, numpart, cntpart, out);
  k_final <<<Bc, 64, 0, stream>>>(logits, amask, labels, startT, endT, Mws, numpart, cntpart, out);
}